// Round 1
// baseline (90.272 us; speedup 1.0000x reference)
//
#include <hip/hip_runtime.h>
#include <math.h>

#define TILE 256

__device__ __forceinline__ float fast_exp2(float x) {
#if __has_builtin(__builtin_amdgcn_exp2f)
    return __builtin_amdgcn_exp2f(x);   // v_exp_f32
#else
    return exp2f(x);
#endif
}

__device__ __forceinline__ float fast_rcp(float x) {
#if __has_builtin(__builtin_amdgcn_rcpf)
    return __builtin_amdgcn_rcpf(x);    // v_rcp_f32
#else
    return 1.0f / x;
#endif
}

// One block per tile-pair (bi <= bj) of the upper triangle.
// bi==bj: full 256x256 tile with relu(t_i - t_j)      (diagonal terms are 0)
// bi< bj: 256x256 tile with |t_i - t_j|, counted once (covers both (i,j),(j,i))
__global__ __launch_bounds__(TILE) void auc_tile_kernel(
    const float* __restrict__ t, const float* __restrict__ p,
    float* __restrict__ block_sums, float* __restrict__ atomic_acc,
    int T_tiles, int use_atomic)
{
    __shared__ float s_p[TILE];
    __shared__ float s_t[TILE];
    __shared__ float s_red[4];

    const int b = blockIdx.x;
    const int T = T_tiles;

    // Map linear block id -> (bi, bj), 0 <= bi <= bj < T.
    // Entries before row r: C(r) = r*T - r*(r-1)/2
    float fT = (float)T + 0.5f;
    int bi = (int)(fT - sqrtf(fT * fT - 2.0f * (float)b));
    if (bi < 0) bi = 0;
    if (bi > T - 1) bi = T - 1;
    while (bi > 0 && (bi * T - (bi * (bi - 1)) / 2) > b) --bi;
    while (((bi + 1) * T - ((bi + 1) * bi) / 2) <= b) ++bi;
    const int row_start = bi * T - (bi * (bi - 1)) / 2;
    const int bj = bi + (b - row_start);

    const int tid = threadIdx.x;
    s_p[tid] = p[bj * TILE + tid];
    s_t[tid] = t[bj * TILE + tid];
    __syncthreads();

    const float p_i = p[bi * TILE + tid];
    const float t_i = t[bi * TILE + tid];
    // sigmoid(x) = 1/(1 + exp(-x)); exp(-x) = exp2(-x*log2(e))
    const float pl = p_i * -1.44269504088896340736f;
    float acc = 0.0f;

    if (bi == bj) {  // block-uniform branch, no divergence
#pragma unroll 8
        for (int j = 0; j < TILE; ++j) {
            float e   = fast_exp2(pl * s_p[j]);
            float sig = fast_rcp(1.0f + e);
            float d   = t_i - s_t[j];
            acc = fmaf(sig, fmaxf(d, 0.0f), acc);
        }
    } else {
#pragma unroll 8
        for (int j = 0; j < TILE; ++j) {
            float e   = fast_exp2(pl * s_p[j]);
            float sig = fast_rcp(1.0f + e);
            float d   = t_i - s_t[j];
            acc = fmaf(sig, fabsf(d), acc);  // |d| folds into src modifier
        }
    }

    // wave(64) shuffle reduce -> 4 partials -> block sum
#pragma unroll
    for (int off = 32; off > 0; off >>= 1)
        acc += __shfl_down(acc, off, 64);
    const int wave = tid >> 6;
    if ((tid & 63) == 0) s_red[wave] = acc;
    __syncthreads();
    if (tid == 0) {
        float bsum = s_red[0] + s_red[1] + s_red[2] + s_red[3];
        if (use_atomic) atomicAdd(atomic_acc, bsum);
        else            block_sums[b] = bsum;
    }
}

__global__ __launch_bounds__(256) void auc_reduce_kernel(
    const float* __restrict__ block_sums, int nb,
    float* __restrict__ out, float neg_inv_n2)
{
    __shared__ float s_red[4];
    float acc = 0.0f;
    for (int i = threadIdx.x; i < nb; i += 256) acc += block_sums[i];
#pragma unroll
    for (int off = 32; off > 0; off >>= 1)
        acc += __shfl_down(acc, off, 64);
    const int wave = threadIdx.x >> 6;
    if ((threadIdx.x & 63) == 0) s_red[wave] = acc;
    __syncthreads();
    if (threadIdx.x == 0)
        out[0] = (s_red[0] + s_red[1] + s_red[2] + s_red[3]) * neg_inv_n2;
}

__global__ void auc_finalize_atomic(const float* __restrict__ acc,
                                    float* __restrict__ out, float neg_inv_n2)
{
    if (threadIdx.x == 0 && blockIdx.x == 0) out[0] = acc[0] * neg_inv_n2;
}

extern "C" void kernel_launch(void* const* d_in, const int* in_sizes, int n_in,
                              void* d_out, int out_size, void* d_ws, size_t ws_size,
                              hipStream_t stream) {
    const float* y_true = (const float*)d_in[0];
    const float* y_pred = (const float*)d_in[1];
    float* out = (float*)d_out;
    const int N = in_sizes[0];           // 16384; assumes N % 256 == 0
    const int T = N / TILE;
    const int nb = T * (T + 1) / 2;      // 2080 tile-pairs
    const float neg_inv_n2 = -1.0f / ((float)N * (float)N);

    if (ws_size >= (size_t)nb * sizeof(float)) {
        // deterministic two-stage reduction through workspace
        float* block_sums = (float*)d_ws;
        auc_tile_kernel<<<nb, TILE, 0, stream>>>(y_true, y_pred, block_sums,
                                                 nullptr, T, 0);
        auc_reduce_kernel<<<1, 256, 0, stream>>>(block_sums, nb, out, neg_inv_n2);
    } else {
        // fallback: single-float atomic accumulator in ws
        float* acc = (float*)d_ws;
        hipMemsetAsync(acc, 0, sizeof(float), stream);  // ws re-poisoned each call
        auc_tile_kernel<<<nb, TILE, 0, stream>>>(y_true, y_pred, nullptr,
                                                 acc, T, 1);
        auc_finalize_atomic<<<1, 64, 0, stream>>>(acc, out, neg_inv_n2);
    }
}

// Round 2
// 89.291 us; speedup vs baseline: 1.0110x; 1.0110x over previous
//
#include <hip/hip_runtime.h>
#include <math.h>

// cost = -(1/N^2) * sum_ij sigmoid(p_i p_j) * relu(t_i - t_j)
//      = -(1/(2 N^2)) * S,  S = sum_ij sigmoid(p_i p_j)*|t_i - t_j|  (ordered pairs)
//
// Separable O(N*B) evaluation:
//   sigmoid(p_i p_j) ~= sum_b w_b(p_j) * sigmoid(p_i * q_b)   (linear interp in p_j)
//   S ~= sum_i sum_b sigmoid(p_i q_b) * M_b(t_i),
//   M_b(t) = sum_j w_b(p_j) |t - t_j|   -- exact at t-grid nodes via binned
//   prefix sums: M_b(g) = g*(2A - Wtot) + (Ptot - 2B), lerped between nodes.
// Error bound ~1.5e-4 vs threshold 1.68e-3.

#define TB 128                 // t-bins (nodes: TB+1)
#define PB 192                 // p-grid points
#define PLO (-5.0f)
#define PHI (5.0f)
#define BCH 4                  // b-chunks in main kernel

// ws float layout:
//   W  [TB][PB]    at 0            (24576)
//   P  [TB][PB]    at 24576        (24576)
//   M  [PB][TB+1]  at 49152        (24768)
//   bsums          at 73920
#define OFF_W 0
#define OFF_P (TB * PB)
#define OFF_M (2 * TB * PB)
#define OFF_BS (2 * TB * PB + PB * (TB + 1))

__global__ __launch_bounds__(256) void k0_zero(float* __restrict__ ws, int n) {
    int i = blockIdx.x * 256 + threadIdx.x;
    if (i < n) ws[i] = 0.0f;
}

__global__ __launch_bounds__(256) void k1_bin(
    const float* __restrict__ t, const float* __restrict__ p,
    float* __restrict__ W, float* __restrict__ Pm, int N)
{
    int i = blockIdx.x * 256 + threadIdx.x;
    if (i >= N) return;
    float pv = p[i], tv = t[i];
    float x = (pv - PLO) * ((float)(PB - 1) / (PHI - PLO));
    x = fminf(fmaxf(x, 0.0f), (float)(PB - 1) - 1e-4f);
    int b0 = (int)x;
    float f = x - (float)b0;
    int tau = (int)(tv * (float)TB);
    tau = min(max(tau, 0), TB - 1);
    float w0 = 1.0f - f;
    atomicAdd(&W[tau * PB + b0],      w0);
    atomicAdd(&W[tau * PB + b0 + 1],  f);
    atomicAdd(&Pm[tau * PB + b0],     w0 * tv);
    atomicAdd(&Pm[tau * PB + b0 + 1], f * tv);
}

// One block of PB threads; thread b builds node values M_b[k], k=0..TB.
__global__ __launch_bounds__(PB) void k2_nodes(
    const float* __restrict__ W, const float* __restrict__ Pm,
    float* __restrict__ M)
{
    int b = threadIdx.x;
    float Wtot = 0.0f, Ptot = 0.0f;
#pragma unroll 16
    for (int tau = 0; tau < TB; ++tau) {
        Wtot += W[tau * PB + b];       // coalesced across threads
        Ptot += Pm[tau * PB + b];
    }
    float A = 0.0f, Bp = 0.0f;
#pragma unroll 8
    for (int k = 0; k <= TB; ++k) {
        float g = (float)k * (1.0f / (float)TB);
        M[b * (TB + 1) + k] = g * (2.0f * A - Wtot) + (Ptot - 2.0f * Bp);
        if (k < TB) {
            A  += W[k * PB + b];
            Bp += Pm[k * PB + b];
        }
    }
}

// grid = (N/256) * BCH blocks; block handles 256 i's x (PB/BCH) grid points.
__global__ __launch_bounds__(256) void k3_main(
    const float* __restrict__ t, const float* __restrict__ p,
    const float* __restrict__ M, float* __restrict__ bsums, int N)
{
    __shared__ float s_red[4];
    const int ic = blockIdx.x >> 2;
    const int bc = blockIdx.x & 3;
    const int i = ic * 256 + threadIdx.x;

    const float pv = p[i], tv = t[i];
    const float c = pv * -1.44269504088896340736f;   // -log2(e) * p_i
    float x = tv * (float)TB;
    int k = (int)x;
    k = min(k, TB - 1);
    const float f = x - (float)k;

    const int nb = PB / BCH;                          // 48
    const int b0 = bc * nb;
    const float h = (PHI - PLO) / (float)(PB - 1);
    float acc = 0.0f;

#pragma unroll 8
    for (int j = 0; j < nb; ++j) {
        const int b = b0 + j;
        const float* Mr = M + b * (TB + 1);
        float m0 = Mr[k];
        float m1 = Mr[k + 1];
        float m = fmaf(f, m1 - m0, m0);               // M_b(t_i)
        float q = PLO + (float)b * h;
        float e = __builtin_amdgcn_exp2f(c * q);      // exp(-p_i q_b)
        float sig = __builtin_amdgcn_rcpf(1.0f + e);  // sigmoid(p_i q_b)
        acc = fmaf(sig, m, acc);
    }

    // wave(64) shuffle reduce -> 4 partials -> block sum
#pragma unroll
    for (int off = 32; off > 0; off >>= 1)
        acc += __shfl_down(acc, off, 64);
    const int wave = threadIdx.x >> 6;
    if ((threadIdx.x & 63) == 0) s_red[wave] = acc;
    __syncthreads();
    if (threadIdx.x == 0)
        bsums[blockIdx.x] = s_red[0] + s_red[1] + s_red[2] + s_red[3];
}

__global__ __launch_bounds__(256) void k4_reduce(
    const float* __restrict__ bsums, int nb,
    float* __restrict__ out, float scale)
{
    __shared__ float s_red[4];
    float acc = 0.0f;
    for (int i = threadIdx.x; i < nb; i += 256) acc += bsums[i];
#pragma unroll
    for (int off = 32; off > 0; off >>= 1)
        acc += __shfl_down(acc, off, 64);
    const int wave = threadIdx.x >> 6;
    if ((threadIdx.x & 63) == 0) s_red[wave] = acc;
    __syncthreads();
    if (threadIdx.x == 0)
        out[0] = (s_red[0] + s_red[1] + s_red[2] + s_red[3]) * scale;
}

extern "C" void kernel_launch(void* const* d_in, const int* in_sizes, int n_in,
                              void* d_out, int out_size, void* d_ws, size_t ws_size,
                              hipStream_t stream) {
    const float* y_true = (const float*)d_in[0];
    const float* y_pred = (const float*)d_in[1];
    float* out = (float*)d_out;
    float* ws  = (float*)d_ws;
    const int N = in_sizes[0];                 // 16384 (multiple of 256)

    float* W  = ws + OFF_W;
    float* Pm = ws + OFF_P;
    float* M  = ws + OFF_M;
    float* bs = ws + OFF_BS;

    const int nzero = 2 * TB * PB;             // W + P
    k0_zero<<<(nzero + 255) / 256, 256, 0, stream>>>(ws, nzero);
    k1_bin<<<(N + 255) / 256, 256, 0, stream>>>(y_true, y_pred, W, Pm, N);
    k2_nodes<<<1, PB, 0, stream>>>(W, Pm, M);
    const int nb3 = (N / 256) * BCH;           // 256 blocks
    k3_main<<<nb3, 256, 0, stream>>>(y_true, y_pred, M, bs, N);
    const float scale = -0.5f / ((float)N * (float)N);
    k4_reduce<<<1, 256, 0, stream>>>(bs, nb3, out, scale);
}